// Round 1
// baseline (5272.478 us; speedup 1.0000x reference)
//
#include <hip/hip_runtime.h>

// Problem constants (match reference)
constexpr int DD = 128, HH = 128, WW = 128;
constexpr int NS = 16, HSL = 128, WSL = 128;
constexpr int VOX = DD * HH * WW;        // 2,097,152
constexpr int NPIX = NS * HSL * WSL;     // 262,144
constexpr float RES_RATIO = 1.5f;

// ---------------------------------------------------------------------------
// Geometry helper: load transform row-major theta[n][3][4] = (R | t)
// pixel base point p = R @ (u, v, 0) + t + center
// sample point s = p + (ix-1)*Rcol0 + (iy-1)*Rcol1 + (iz-1)*Rcol2
// ---------------------------------------------------------------------------

// A: PSF-weighted trilinear gather volume -> slices
__global__ __launch_bounds__(256) void a_kernel(
    const float* __restrict__ theta, const float* __restrict__ vol,
    const float* __restrict__ psf, float* __restrict__ out)
{
    int idx = blockIdx.x * 256 + threadIdx.x;     // exact grid: NPIX threads
    int w = idx & 127;
    int h = (idx >> 7) & 127;
    int n = idx >> 14;
    const float* T = theta + n * 12;
    float r00 = T[0], r01 = T[1], r02 = T[2],  t0 = T[3];
    float r10 = T[4], r11 = T[5], r12 = T[6],  t1 = T[7];
    float r20 = T[8], r21 = T[9], r22 = T[10], t2 = T[11];

    float u = (w - 63.5f) * RES_RATIO;
    float v = (h - 63.5f) * RES_RATIO;
    float px = fmaf(r00, u, fmaf(r01, v, t0)) + 63.5f;
    float py = fmaf(r10, u, fmaf(r11, v, t1)) + 63.5f;
    float pz = fmaf(r20, u, fmaf(r21, v, t2)) + 63.5f;

    // pixel-level cull: |R@off| <= sqrt(3) ~ 1.7321; contribution needs coord in (-1,128)
    if (px <= -2.74f || px >= 129.74f || py <= -2.74f || py >= 129.74f ||
        pz <= -2.74f || pz >= 129.74f) {
        out[idx] = 0.0f;
        return;
    }

    float acc = 0.0f;
    for (int iz = 0; iz < 3; ++iz)
    for (int iy = 0; iy < 3; ++iy)
    for (int ix = 0; ix < 3; ++ix) {
        float ox = (float)(ix - 1), oy = (float)(iy - 1), oz = (float)(iz - 1);
        float sx = px + ox * r00 + oy * r01 + oz * r02;
        float sy = py + ox * r10 + oy * r11 + oz * r12;
        float sz = pz + ox * r20 + oy * r21 + oz * r22;
        if (sx <= -1.0f || sx >= 128.0f || sy <= -1.0f || sy >= 128.0f ||
            sz <= -1.0f || sz >= 128.0f) continue;
        float pw = psf[(iz * 3 + iy) * 3 + ix];

        float xf = floorf(sx), yf = floorf(sy), zf = floorf(sz);
        int x0 = (int)xf, y0 = (int)yf, z0 = (int)zf;
        float fx = sx - xf, fy = sy - yf, fz = sz - zf;
        float wx0 = 1.0f - fx, wy0 = 1.0f - fy, wz0 = 1.0f - fz;

        #pragma unroll
        for (int dz = 0; dz < 2; ++dz)
        #pragma unroll
        for (int dy = 0; dy < 2; ++dy)
        #pragma unroll
        for (int dx = 0; dx < 2; ++dx) {
            int xi = x0 + dx, yi = y0 + dy, zi = z0 + dz;
            bool inb = ((unsigned)xi < 128u) & ((unsigned)yi < 128u) & ((unsigned)zi < 128u);
            if (inb) {
                float wgt = (dx ? fx : wx0) * (dy ? fy : wy0) * (dz ? fz : wz0);
                acc += pw * wgt * vol[(zi << 14) + (yi << 7) + xi];
            }
        }
    }
    out[idx] = acc;
}

// At: PSF-weighted trilinear scatter-add slices -> volume (vol must be pre-zeroed)
__global__ __launch_bounds__(256) void at_kernel(
    const float* __restrict__ theta, const float* __restrict__ sl,
    const float* __restrict__ psf, float* __restrict__ vol)
{
    int idx = blockIdx.x * 256 + threadIdx.x;
    int w = idx & 127;
    int h = (idx >> 7) & 127;
    int n = idx >> 14;
    const float* T = theta + n * 12;
    float r00 = T[0], r01 = T[1], r02 = T[2],  t0 = T[3];
    float r10 = T[4], r11 = T[5], r12 = T[6],  t1 = T[7];
    float r20 = T[8], r21 = T[9], r22 = T[10], t2 = T[11];

    float u = (w - 63.5f) * RES_RATIO;
    float v = (h - 63.5f) * RES_RATIO;
    float px = fmaf(r00, u, fmaf(r01, v, t0)) + 63.5f;
    float py = fmaf(r10, u, fmaf(r11, v, t1)) + 63.5f;
    float pz = fmaf(r20, u, fmaf(r21, v, t2)) + 63.5f;

    if (px <= -2.74f || px >= 129.74f || py <= -2.74f || py >= 129.74f ||
        pz <= -2.74f || pz >= 129.74f) return;

    float sval = sl[idx];

    for (int iz = 0; iz < 3; ++iz)
    for (int iy = 0; iy < 3; ++iy)
    for (int ix = 0; ix < 3; ++ix) {
        float ox = (float)(ix - 1), oy = (float)(iy - 1), oz = (float)(iz - 1);
        float sx = px + ox * r00 + oy * r01 + oz * r02;
        float sy = py + ox * r10 + oy * r11 + oz * r12;
        float sz = pz + ox * r20 + oy * r21 + oz * r22;
        if (sx <= -1.0f || sx >= 128.0f || sy <= -1.0f || sy >= 128.0f ||
            sz <= -1.0f || sz >= 128.0f) continue;
        float pw = psf[(iz * 3 + iy) * 3 + ix];
        float val = sval * pw;

        float xf = floorf(sx), yf = floorf(sy), zf = floorf(sz);
        int x0 = (int)xf, y0 = (int)yf, z0 = (int)zf;
        float fx = sx - xf, fy = sy - yf, fz = sz - zf;
        float wx0 = 1.0f - fx, wy0 = 1.0f - fy, wz0 = 1.0f - fz;

        #pragma unroll
        for (int dz = 0; dz < 2; ++dz)
        #pragma unroll
        for (int dy = 0; dy < 2; ++dy)
        #pragma unroll
        for (int dx = 0; dx < 2; ++dx) {
            int xi = x0 + dx, yi = y0 + dy, zi = z0 + dz;
            bool inb = ((unsigned)xi < 128u) & ((unsigned)yi < 128u) & ((unsigned)zi < 128u);
            if (inb) {
                float wgt = (dx ? fx : wx0) * (dy ? fy : wy0) * (dz ? fz : wz0);
                atomicAdd(&vol[(zi << 14) + (yi << 7) + xi], wgt * val);
            }
        }
    }
}

// r = b - Ap; p = r
__global__ __launch_bounds__(256) void rp_init_kernel(
    float* __restrict__ r, float* __restrict__ p,
    const float* __restrict__ b, const float* __restrict__ Ap)
{
    int i = blockIdx.x * 256 + threadIdx.x;
    float rv = b[i] - Ap[i];
    r[i] = rv;
    p[i] = rv;
}

// out += sum(a[i] * b[i]) in double, one atomicAdd per block
__global__ __launch_bounds__(256) void dot_kernel(
    const float* __restrict__ a, const float* __restrict__ b,
    int n, double* __restrict__ out)
{
    double s = 0.0;
    for (int i = blockIdx.x * 256 + threadIdx.x; i < n; i += gridDim.x * 256)
        s += (double)a[i] * (double)b[i];
    #pragma unroll
    for (int off = 32; off > 0; off >>= 1)
        s += __shfl_down(s, off, 64);
    __shared__ double ls[4];
    int wid = threadIdx.x >> 6;
    if ((threadIdx.x & 63) == 0) ls[wid] = s;
    __syncthreads();
    if (threadIdx.x == 0) {
        atomicAdd(out, ls[0] + ls[1] + ls[2] + ls[3]);
    }
}

// x += alpha*p; r -= alpha*Ap;  alpha = rr_old / pAp
__global__ __launch_bounds__(256) void update_xr_kernel(
    float* __restrict__ x, float* __restrict__ r,
    const float* __restrict__ p, const float* __restrict__ Ap,
    const double* __restrict__ rr_old, const double* __restrict__ pAp)
{
    float alpha = (float)(*rr_old / *pAp);
    int i = blockIdx.x * 256 + threadIdx.x;
    x[i] = fmaf(alpha, p[i], x[i]);
    r[i] = fmaf(-alpha, Ap[i], r[i]);
}

// p = r + beta*p;  beta = rr_new / rr_old
__global__ __launch_bounds__(256) void update_p_kernel(
    float* __restrict__ p, const float* __restrict__ r,
    const double* __restrict__ rr_new, const double* __restrict__ rr_old)
{
    float beta = (float)(*rr_new / *rr_old);
    int i = blockIdx.x * 256 + threadIdx.x;
    p[i] = fmaf(beta, p[i], r[i]);
}

__global__ __launch_bounds__(256) void relu_kernel(
    float* __restrict__ out, const float* __restrict__ x)
{
    int i = blockIdx.x * 256 + threadIdx.x;
    out[i] = fmaxf(x[i], 0.0f);
}

extern "C" void kernel_launch(void* const* d_in, const int* in_sizes, int n_in,
                              void* d_out, int out_size, void* d_ws, size_t ws_size,
                              hipStream_t stream) {
    const float* theta  = (const float*)d_in[0];  // [16,3,4]
    const float* slices = (const float*)d_in[1];  // [16,1,128,128]
    const float* volume = (const float*)d_in[2];  // [1,1,128,128,128]
    const float* psf    = (const float*)d_in[3];  // [3,3,3]
    float* out = (float*)d_out;

    char* ws = (char*)d_ws;
    float* x  = (float*)ws;
    float* r  = x  + VOX;
    float* p  = r  + VOX;
    float* Ap = p  + VOX;
    float* b  = Ap + VOX;
    float* sl = b  + VOX;
    double* sc = (double*)(sl + NPIX);  // sc[0],sc[1]: rr ping-pong; sc[2]: pAp

    const int gpix = NPIX / 256;  // 1024
    const int gvox = VOX / 256;   // 8192
    const int gdot = 1024;

    // x = volume (initial guess)
    hipMemcpyAsync(x, volume, VOX * sizeof(float), hipMemcpyDeviceToDevice, stream);

    // b = At(slices)
    hipMemsetAsync(b, 0, VOX * sizeof(float), stream);
    at_kernel<<<gpix, 256, 0, stream>>>(theta, slices, psf, b);

    // Ap = AtA(x0)
    a_kernel<<<gpix, 256, 0, stream>>>(theta, x, psf, sl);
    hipMemsetAsync(Ap, 0, VOX * sizeof(float), stream);
    at_kernel<<<gpix, 256, 0, stream>>>(theta, sl, psf, Ap);

    // r = b - Ap; p = r
    rp_init_kernel<<<gvox, 256, 0, stream>>>(r, p, b, Ap);

    // rr0 = dot(r, r)
    hipMemsetAsync(&sc[0], 0, sizeof(double), stream);
    dot_kernel<<<gdot, 256, 0, stream>>>(r, r, VOX, &sc[0]);

    for (int it = 0; it < 10; ++it) {
        double* rr_old = &sc[it & 1];
        double* rr_new = &sc[(it + 1) & 1];
        double* pap    = &sc[2];

        // Ap = AtA(p)
        a_kernel<<<gpix, 256, 0, stream>>>(theta, p, psf, sl);
        hipMemsetAsync(Ap, 0, VOX * sizeof(float), stream);
        at_kernel<<<gpix, 256, 0, stream>>>(theta, sl, psf, Ap);

        // pAp = dot(p, Ap)
        hipMemsetAsync(pap, 0, sizeof(double), stream);
        dot_kernel<<<gdot, 256, 0, stream>>>(p, Ap, VOX, pap);

        // x += alpha p; r -= alpha Ap
        update_xr_kernel<<<gvox, 256, 0, stream>>>(x, r, p, Ap, rr_old, pap);

        // rr_new = dot(r, r)
        hipMemsetAsync(rr_new, 0, sizeof(double), stream);
        dot_kernel<<<gdot, 256, 0, stream>>>(r, r, VOX, rr_new);

        // p = r + beta p
        update_p_kernel<<<gvox, 256, 0, stream>>>(p, r, rr_new, rr_old);
    }

    // out = relu(x)
    relu_kernel<<<gvox, 256, 0, stream>>>(out, x);
}

// Round 2
// 3264.740 us; speedup vs baseline: 1.6150x; 1.6150x over previous
//
#include <hip/hip_runtime.h>
#include <math.h>

// Problem constants (match reference)
constexpr int DD = 128, HH = 128, WW = 128;
constexpr int NS = 16, HSL = 128, WSL = 128;
constexpr int VOX = DD * HH * WW;        // 2,097,152
constexpr int NPIX = NS * HSL * WSL;     // 262,144
constexpr float RES_RATIO = 1.5f;
constexpr float SQRT3 = 1.7320509f;      // candidate tolerance (|m - R^T g|_inf < sqrt3)

// ---------------------------------------------------------------------------
// A: PSF-weighted trilinear gather volume -> slices (one thread per pixel)
// ---------------------------------------------------------------------------
__global__ __launch_bounds__(256) void a_kernel(
    const float* __restrict__ theta, const float* __restrict__ vol,
    const float* __restrict__ psf, float* __restrict__ out)
{
    int idx = blockIdx.x * 256 + threadIdx.x;     // exact grid: NPIX threads
    int w = idx & 127;
    int h = (idx >> 7) & 127;
    int n = idx >> 14;
    const float* T = theta + n * 12;
    float r00 = T[0], r01 = T[1], r02 = T[2],  t0 = T[3];
    float r10 = T[4], r11 = T[5], r12 = T[6],  t1 = T[7];
    float r20 = T[8], r21 = T[9], r22 = T[10], t2 = T[11];

    float u = (w - 63.5f) * RES_RATIO;
    float v = (h - 63.5f) * RES_RATIO;
    float px = fmaf(r00, u, fmaf(r01, v, t0)) + 63.5f;
    float py = fmaf(r10, u, fmaf(r11, v, t1)) + 63.5f;
    float pz = fmaf(r20, u, fmaf(r21, v, t2)) + 63.5f;

    if (px <= -2.74f || px >= 129.74f || py <= -2.74f || py >= 129.74f ||
        pz <= -2.74f || pz >= 129.74f) {
        out[idx] = 0.0f;
        return;
    }

    float acc = 0.0f;
    for (int iz = 0; iz < 3; ++iz)
    for (int iy = 0; iy < 3; ++iy)
    for (int ix = 0; ix < 3; ++ix) {
        float ox = (float)(ix - 1), oy = (float)(iy - 1), oz = (float)(iz - 1);
        float sx = px + ox * r00 + oy * r01 + oz * r02;
        float sy = py + ox * r10 + oy * r11 + oz * r12;
        float sz = pz + ox * r20 + oy * r21 + oz * r22;
        if (sx <= -1.0f || sx >= 128.0f || sy <= -1.0f || sy >= 128.0f ||
            sz <= -1.0f || sz >= 128.0f) continue;
        float pw = psf[(iz * 3 + iy) * 3 + ix];

        float xf = floorf(sx), yf = floorf(sy), zf = floorf(sz);
        int x0 = (int)xf, y0 = (int)yf, z0 = (int)zf;
        float fx = sx - xf, fy = sy - yf, fz = sz - zf;
        float wx0 = 1.0f - fx, wy0 = 1.0f - fy, wz0 = 1.0f - fz;

        #pragma unroll
        for (int dz = 0; dz < 2; ++dz)
        #pragma unroll
        for (int dy = 0; dy < 2; ++dy)
        #pragma unroll
        for (int dx = 0; dx < 2; ++dx) {
            int xi = x0 + dx, yi = y0 + dy, zi = z0 + dz;
            bool inb = ((unsigned)xi < 128u) & ((unsigned)yi < 128u) & ((unsigned)zi < 128u);
            if (inb) {
                float wgt = (dx ? fx : wx0) * (dy ? fy : wy0) * (dz ? fz : wz0);
                acc += pw * wgt * vol[(zi << 14) + (yi << 7) + xi];
            }
        }
    }
    out[idx] = acc;
}

// ---------------------------------------------------------------------------
// At as a GATHER: one thread per voxel, no atomics.
// For voxel q, slice n: g = q - (t + center); g' = R^T g.
// Lattice point m = (1.5*(w-63.5)+ox, 1.5*(h-63.5)+oy, oz) contributes
// tri(Rm - g) * psf[oz][oy][ox] * sl[n][h][w]  when |Rm - g|_inf < 1.
// |Rm - g|_inf < 1  =>  |m - g'|_inf < sqrt(3)  (rotation preserves L2 norm),
// so candidate (w,ox,h,oy,oz) enumeration via the rotated frame is a superset.
// Writes every voxel -> output needs no pre-zeroing.
// ---------------------------------------------------------------------------
__global__ __launch_bounds__(256) void at_gather_kernel(
    const float* __restrict__ theta, const float* __restrict__ sl,
    const float* __restrict__ psf, float* __restrict__ vol)
{
    __shared__ float spsf[27];
    if (threadIdx.x < 27) spsf[threadIdx.x] = psf[threadIdx.x];
    __syncthreads();

    int idx = blockIdx.x * 256 + threadIdx.x;     // exact grid: VOX threads
    float qx = (float)(idx & 127);
    float qy = (float)((idx >> 7) & 127);
    float qz = (float)(idx >> 14);

    float acc = 0.0f;
    for (int n = 0; n < NS; ++n) {
        const float* T = theta + n * 12;
        float r00 = T[0], r01 = T[1], r02 = T[2],  t0 = T[3];
        float r10 = T[4], r11 = T[5], r12 = T[6],  t1 = T[7];
        float r20 = T[8], r21 = T[9], r22 = T[10], t2 = T[11];

        float gx = qx - (t0 + 63.5f);
        float gy = qy - (t1 + 63.5f);
        float gz = qz - (t2 + 63.5f);
        // g' = R^T g
        float gpx = r00 * gx + r10 * gy + r20 * gz;
        float gpy = r01 * gx + r11 * gy + r21 * gz;
        float gpz = r02 * gx + r12 * gy + r22 * gz;

        // slab / FOV cull (necessary conditions)
        if (fabsf(gpz) >= 1.0f + SQRT3) continue;
        if (fabsf(gpx) >= 96.25f + SQRT3) continue;
        if (fabsf(gpy) >= 96.25f + SQRT3) continue;

        // candidate w range: |1.5*(w-63.5) - gpx| < 1 + sqrt3
        const float inv15 = 1.0f / 1.5f;
        int wlo = (int)ceilf(63.5f + (gpx - (1.0f + SQRT3)) * inv15);
        int whi = (int)floorf(63.5f + (gpx + (1.0f + SQRT3)) * inv15);
        wlo = max(wlo, 0); whi = min(whi, 127);
        int hlo = (int)ceilf(63.5f + (gpy - (1.0f + SQRT3)) * inv15);
        int hhi = (int)floorf(63.5f + (gpy + (1.0f + SQRT3)) * inv15);
        hlo = max(hlo, 0); hhi = min(hhi, 127);

        // oz candidates
        bool zok[3];
        #pragma unroll
        for (int iz = 0; iz < 3; ++iz)
            zok[iz] = fabsf((float)(iz - 1) - gpz) < SQRT3;

        const float* slice_n = sl + (n << 14);

        for (int w = wlo; w <= whi; ++w) {
            float u = (w - 63.5f) * RES_RATIO;
            #pragma unroll
            for (int ix = 0; ix < 3; ++ix) {
                float mu = u + (float)(ix - 1);
                if (fabsf(mu - gpx) >= SQRT3) continue;
                // partial e = Rcol0 * mu - g
                float Ax = fmaf(r00, mu, -gx);
                float Ay = fmaf(r10, mu, -gy);
                float Az = fmaf(r20, mu, -gz);
                for (int h = hlo; h <= hhi; ++h) {
                    float v = (h - 63.5f) * RES_RATIO;
                    float sval = slice_n[(h << 7) + w];
                    #pragma unroll
                    for (int iy = 0; iy < 3; ++iy) {
                        float mv = v + (float)(iy - 1);
                        if (fabsf(mv - gpy) >= SQRT3) continue;
                        float Bx = fmaf(r01, mv, Ax);
                        float By = fmaf(r11, mv, Ay);
                        float Bz = fmaf(r21, mv, Az);
                        #pragma unroll
                        for (int iz = 0; iz < 3; ++iz) {
                            if (!zok[iz]) continue;
                            float moz = (float)(iz - 1);
                            float ex = fmaf(r02, moz, Bx);
                            float ey = fmaf(r12, moz, By);
                            float ez = fmaf(r22, moz, Bz);
                            float wx = 1.0f - fabsf(ex);
                            float wy = 1.0f - fabsf(ey);
                            float wz = 1.0f - fabsf(ez);
                            if (wx > 0.0f && wy > 0.0f && wz > 0.0f) {
                                float wgt = wx * wy * wz;
                                float pw = spsf[(iz * 3 + iy) * 3 + ix];
                                acc = fmaf(wgt * pw, sval, acc);
                            }
                        }
                    }
                }
            }
        }
    }
    vol[idx] = acc;
}

// r = b - Ap; p = r
__global__ __launch_bounds__(256) void rp_init_kernel(
    float* __restrict__ r, float* __restrict__ p,
    const float* __restrict__ b, const float* __restrict__ Ap)
{
    int i = blockIdx.x * 256 + threadIdx.x;
    float rv = b[i] - Ap[i];
    r[i] = rv;
    p[i] = rv;
}

// out += sum(a[i] * b[i]) in double, one atomicAdd per block
__global__ __launch_bounds__(256) void dot_kernel(
    const float* __restrict__ a, const float* __restrict__ b,
    int n, double* __restrict__ out)
{
    double s = 0.0;
    for (int i = blockIdx.x * 256 + threadIdx.x; i < n; i += gridDim.x * 256)
        s += (double)a[i] * (double)b[i];
    #pragma unroll
    for (int off = 32; off > 0; off >>= 1)
        s += __shfl_down(s, off, 64);
    __shared__ double ls[4];
    int wid = threadIdx.x >> 6;
    if ((threadIdx.x & 63) == 0) ls[wid] = s;
    __syncthreads();
    if (threadIdx.x == 0) {
        atomicAdd(out, ls[0] + ls[1] + ls[2] + ls[3]);
    }
}

// x += alpha*p; r -= alpha*Ap;  alpha = rr_old / pAp
__global__ __launch_bounds__(256) void update_xr_kernel(
    float* __restrict__ x, float* __restrict__ r,
    const float* __restrict__ p, const float* __restrict__ Ap,
    const double* __restrict__ rr_old, const double* __restrict__ pAp)
{
    float alpha = (float)(*rr_old / *pAp);
    int i = blockIdx.x * 256 + threadIdx.x;
    x[i] = fmaf(alpha, p[i], x[i]);
    r[i] = fmaf(-alpha, Ap[i], r[i]);
}

// p = r + beta*p;  beta = rr_new / rr_old
__global__ __launch_bounds__(256) void update_p_kernel(
    float* __restrict__ p, const float* __restrict__ r,
    const double* __restrict__ rr_new, const double* __restrict__ rr_old)
{
    float beta = (float)(*rr_new / *rr_old);
    int i = blockIdx.x * 256 + threadIdx.x;
    p[i] = fmaf(beta, p[i], r[i]);
}

__global__ __launch_bounds__(256) void relu_kernel(
    float* __restrict__ out, const float* __restrict__ x)
{
    int i = blockIdx.x * 256 + threadIdx.x;
    out[i] = fmaxf(x[i], 0.0f);
}

extern "C" void kernel_launch(void* const* d_in, const int* in_sizes, int n_in,
                              void* d_out, int out_size, void* d_ws, size_t ws_size,
                              hipStream_t stream) {
    const float* theta  = (const float*)d_in[0];  // [16,3,4]
    const float* slices = (const float*)d_in[1];  // [16,1,128,128]
    const float* volume = (const float*)d_in[2];  // [1,1,128,128,128]
    const float* psf    = (const float*)d_in[3];  // [3,3,3]
    float* out = (float*)d_out;

    char* ws = (char*)d_ws;
    float* x  = (float*)ws;
    float* r  = x  + VOX;
    float* p  = r  + VOX;
    float* Ap = p  + VOX;
    float* b  = Ap + VOX;
    float* sl = b  + VOX;
    double* sc = (double*)(sl + NPIX);  // sc[0],sc[1]: rr ping-pong; sc[2]: pAp

    const int gpix = NPIX / 256;  // 1024
    const int gvox = VOX / 256;   // 8192
    const int gdot = 1024;

    // x = volume (initial guess)
    hipMemcpyAsync(x, volume, VOX * sizeof(float), hipMemcpyDeviceToDevice, stream);

    // b = At(slices)   (gather: fully overwrites, no memset needed)
    at_gather_kernel<<<gvox, 256, 0, stream>>>(theta, slices, psf, b);

    // Ap = AtA(x0)
    a_kernel<<<gpix, 256, 0, stream>>>(theta, x, psf, sl);
    at_gather_kernel<<<gvox, 256, 0, stream>>>(theta, sl, psf, Ap);

    // r = b - Ap; p = r
    rp_init_kernel<<<gvox, 256, 0, stream>>>(r, p, b, Ap);

    // rr0 = dot(r, r)
    hipMemsetAsync(&sc[0], 0, sizeof(double), stream);
    dot_kernel<<<gdot, 256, 0, stream>>>(r, r, VOX, &sc[0]);

    for (int it = 0; it < 10; ++it) {
        double* rr_old = &sc[it & 1];
        double* rr_new = &sc[(it + 1) & 1];
        double* pap    = &sc[2];

        // Ap = AtA(p)
        a_kernel<<<gpix, 256, 0, stream>>>(theta, p, psf, sl);
        at_gather_kernel<<<gvox, 256, 0, stream>>>(theta, sl, psf, Ap);

        // pAp = dot(p, Ap)
        hipMemsetAsync(pap, 0, sizeof(double), stream);
        dot_kernel<<<gdot, 256, 0, stream>>>(p, Ap, VOX, pap);

        // x += alpha p; r -= alpha Ap
        update_xr_kernel<<<gvox, 256, 0, stream>>>(x, r, p, Ap, rr_old, pap);

        // rr_new = dot(r, r)
        hipMemsetAsync(rr_new, 0, sizeof(double), stream);
        dot_kernel<<<gdot, 256, 0, stream>>>(r, r, VOX, rr_new);

        // p = r + beta p
        update_p_kernel<<<gvox, 256, 0, stream>>>(p, r, rr_new, rr_old);
    }

    // out = relu(x)
    relu_kernel<<<gvox, 256, 0, stream>>>(out, x);
}

// Round 3
// 2075.286 us; speedup vs baseline: 2.5406x; 1.5732x over previous
//
#include <hip/hip_runtime.h>
#include <math.h>

// Problem constants (match reference)
constexpr int DD = 128, HH = 128, WW = 128;
constexpr int NS = 16, HSL = 128, WSL = 128;
constexpr int VOX = DD * HH * WW;        // 2,097,152
constexpr int NPIX = NS * HSL * WSL;     // 262,144
constexpr float RES_RATIO = 1.5f;

// Per-slice constant block layout (floats, stride 128):
//  [0..11]  T row-major (r00 r01 r02 t0 | r10 r11 r12 t1 | r20 r21 r22 t2)
//  [12..14] tc = t + 63.5 (volume-center shift folded in)
//  [15..17] C0,C1,C2 = column L1 norms of R (exact At candidate bounds)
//  [18..20] m0,m1,m2 = row L1 norms of R (A pixel-cull margins)
//  [24+3k+{0,1,2}] rotated PSF offset k: R @ (ix-1, iy-1, iz-1), k=(iz*3+iy)*3+ix
constexpr int CSTR = 128;

__global__ __launch_bounds__(512) void prep_kernel(
    const float* __restrict__ theta, float* __restrict__ cst)
{
    int tid = threadIdx.x;
    int n = tid >> 5, j = tid & 31;
    if (n >= NS) return;
    const float* T = theta + n * 12;
    float* C = cst + n * CSTR;
    if (j < 12) C[j] = T[j];
    if (j == 12) {
        float r00=T[0], r01=T[1], r02=T[2],  t0=T[3];
        float r10=T[4], r11=T[5], r12=T[6],  t1=T[7];
        float r20=T[8], r21=T[9], r22=T[10], t2=T[11];
        C[12] = t0 + 63.5f; C[13] = t1 + 63.5f; C[14] = t2 + 63.5f;
        C[15] = fabsf(r00) + fabsf(r10) + fabsf(r20);  // col-x L1
        C[16] = fabsf(r01) + fabsf(r11) + fabsf(r21);  // col-y L1
        C[17] = fabsf(r02) + fabsf(r12) + fabsf(r22);  // col-z L1
        C[18] = fabsf(r00) + fabsf(r01) + fabsf(r02);  // row-x L1
        C[19] = fabsf(r10) + fabsf(r11) + fabsf(r12);  // row-y L1
        C[20] = fabsf(r20) + fabsf(r21) + fabsf(r22);  // row-z L1
    }
    if (j < 27) {
        float ox = (float)(j % 3) - 1.0f;
        float oy = (float)((j / 3) % 3) - 1.0f;
        float oz = (float)(j / 9) - 1.0f;
        C[24 + 3*j + 0] = T[0]*ox + T[1]*oy + T[2]*oz;
        C[24 + 3*j + 1] = T[4]*ox + T[5]*oy + T[6]*oz;
        C[24 + 3*j + 2] = T[8]*ox + T[9]*oy + T[10]*oz;
    }
}

// ---------------------------------------------------------------------------
// Spread-slot double reduction: 64 slots, 256B apart (parallel L2 lines).
// ---------------------------------------------------------------------------
__device__ __forceinline__ void block_reduce_spread(double s, double* slots)
{
    #pragma unroll
    for (int off = 32; off > 0; off >>= 1)
        s += __shfl_down(s, off, 64);
    __shared__ double ls[4];
    if ((threadIdx.x & 63) == 0) ls[threadIdx.x >> 6] = s;
    __syncthreads();
    if (threadIdx.x == 0)
        atomicAdd(&slots[(blockIdx.x & 63) * 32], ls[0] + ls[1] + ls[2] + ls[3]);
}

__device__ __forceinline__ double sum_slots(const double* __restrict__ s)
{
    double t = 0.0;
    #pragma unroll
    for (int i = 0; i < 64; ++i) t += s[i * 32];
    return t;
}

// ---------------------------------------------------------------------------
// A: PSF-weighted trilinear gather volume -> slices (one thread per pixel)
// ---------------------------------------------------------------------------
__global__ __launch_bounds__(256) void a_kernel(
    const float* __restrict__ cst, const float* __restrict__ vol,
    const float* __restrict__ psf, float* __restrict__ out)
{
    int idx = blockIdx.x * 256 + threadIdx.x;     // exact grid: NPIX threads
    int w = idx & 127;
    int h = (idx >> 7) & 127;
    int n = idx >> 14;
    const float* C = cst + n * CSTR;
    float r00=C[0], r01=C[1];
    float r10=C[4], r11=C[5];
    float r20=C[8], r21=C[9];

    float u = (w - 63.5f) * RES_RATIO;
    float v = (h - 63.5f) * RES_RATIO;
    float px = fmaf(r00, u, fmaf(r01, v, C[12]));
    float py = fmaf(r10, u, fmaf(r11, v, C[13]));
    float pz = fmaf(r20, u, fmaf(r21, v, C[14]));

    // pixel cull: sample = p + rotoff, |rotoff_i| <= row L1; need coord in (-1,128)
    if (px <= -1.0f - C[18] || px >= 128.0f + C[18] ||
        py <= -1.0f - C[19] || py >= 128.0f + C[19] ||
        pz <= -1.0f - C[20] || pz >= 128.0f + C[20]) {
        out[idx] = 0.0f;
        return;
    }

    float acc = 0.0f;
    for (int k = 0; k < 27; ++k) {
        float sx = px + C[24 + 3*k + 0];
        float sy = py + C[24 + 3*k + 1];
        float sz = pz + C[24 + 3*k + 2];
        if (sx <= -1.0f || sx >= 128.0f || sy <= -1.0f || sy >= 128.0f ||
            sz <= -1.0f || sz >= 128.0f) continue;
        float pw = psf[k];

        float xf = floorf(sx), yf = floorf(sy), zf = floorf(sz);
        int x0 = (int)xf, y0 = (int)yf, z0 = (int)zf;
        float fx = sx - xf, fy = sy - yf, fz = sz - zf;

        if (x0 >= 0 && x0 < 127 && y0 >= 0 && y0 < 127 && z0 >= 0 && z0 < 127) {
            const float* vp = vol + (z0 << 14) + (y0 << 7) + x0;
            float c000 = vp[0],       c001 = vp[1];
            float c010 = vp[128],     c011 = vp[129];
            float c100 = vp[16384],   c101 = vp[16385];
            float c110 = vp[16512],   c111 = vp[16513];
            float c00 = fmaf(fx, c001 - c000, c000);
            float c01 = fmaf(fx, c011 - c010, c010);
            float c10 = fmaf(fx, c101 - c100, c100);
            float c11 = fmaf(fx, c111 - c110, c110);
            float c0  = fmaf(fy, c01 - c00, c00);
            float c1  = fmaf(fy, c11 - c10, c10);
            acc = fmaf(pw, fmaf(fz, c1 - c0, c0), acc);
        } else {
            float wx0 = 1.0f - fx, wy0 = 1.0f - fy, wz0 = 1.0f - fz;
            #pragma unroll
            for (int dz = 0; dz < 2; ++dz)
            #pragma unroll
            for (int dy = 0; dy < 2; ++dy)
            #pragma unroll
            for (int dx = 0; dx < 2; ++dx) {
                int xi = x0 + dx, yi = y0 + dy, zi = z0 + dz;
                bool inb = ((unsigned)xi < 128u) & ((unsigned)yi < 128u) & ((unsigned)zi < 128u);
                if (inb) {
                    float wgt = (dx ? fx : wx0) * (dy ? fy : wy0) * (dz ? fz : wz0);
                    acc += pw * wgt * vol[(zi << 14) + (yi << 7) + xi];
                }
            }
        }
    }
    out[idx] = acc;
}

// ---------------------------------------------------------------------------
// At as a GATHER with exact L1-column bounds; optional fused dot(dvec, At@sl).
// For voxel q: g = q - tc; g' = R^T g. Candidate m=(mu,mv,oz) must satisfy
// |m_i - g'_i| < Ci (column L1 norm) — exact necessary condition for
// tri(Rm - g) > 0. Weight computed exactly; zero-weight candidates rejected.
// ---------------------------------------------------------------------------
__global__ __launch_bounds__(256) void at_gather_kernel(
    const float* __restrict__ cst, const float* __restrict__ sl,
    const float* __restrict__ psf, float* __restrict__ vol,
    const float* __restrict__ dvec, double* __restrict__ dslots)
{
    __shared__ float spsf[27];
    if (threadIdx.x < 27) spsf[threadIdx.x] = psf[threadIdx.x];
    __syncthreads();

    int idx = blockIdx.x * 256 + threadIdx.x;     // exact grid: VOX threads
    float qx = (float)(idx & 127);
    float qy = (float)((idx >> 7) & 127);
    float qz = (float)(idx >> 14);

    float acc = 0.0f;
    for (int n = 0; n < NS; ++n) {
        const float* C = cst + n * CSTR;
        float r00=C[0], r01=C[1], r02=C[2];
        float r10=C[4], r11=C[5], r12=C[6];
        float r20=C[8], r21=C[9], r22=C[10];
        float gx = qx - C[12], gy = qy - C[13], gz = qz - C[14];
        float C0 = C[15], C1 = C[16], C2 = C[17];

        float gpz = r02*gx + r12*gy + r22*gz;
        if (fabsf(gpz) >= 1.0f + C2) continue;
        float gpx = r00*gx + r10*gy + r20*gz;
        if (fabsf(gpx) >= 96.25f + C0) continue;
        float gpy = r01*gx + r11*gy + r21*gz;
        if (fabsf(gpy) >= 96.25f + C1) continue;

        const float inv15 = 1.0f / 1.5f;
        float Bx = 1.0f + C0, By = 1.0f + C1;
        int wlo = (int)ceilf (63.5f + (gpx - Bx) * inv15);
        int whi = (int)floorf(63.5f + (gpx + Bx) * inv15);
        wlo = max(wlo, 0); whi = min(whi, 127);
        int hlo = (int)ceilf (63.5f + (gpy - By) * inv15);
        int hhi = (int)floorf(63.5f + (gpy + By) * inv15);
        hlo = max(hlo, 0); hhi = min(hhi, 127);

        bool zok[3];
        #pragma unroll
        for (int iz = 0; iz < 3; ++iz)
            zok[iz] = fabsf((float)(iz - 1) - gpz) < C2;

        const float* slice_n = sl + (n << 14);

        for (int w = wlo; w <= whi; ++w) {
            float u = (w - 63.5f) * RES_RATIO;
            #pragma unroll
            for (int ix = 0; ix < 3; ++ix) {
                float mu = u + (float)(ix - 1);
                if (fabsf(mu - gpx) >= C0) continue;
                float Ax = fmaf(r00, mu, -gx);
                float Ay = fmaf(r10, mu, -gy);
                float Az = fmaf(r20, mu, -gz);
                for (int h = hlo; h <= hhi; ++h) {
                    float v = (h - 63.5f) * RES_RATIO;
                    float sval = slice_n[(h << 7) + w];
                    #pragma unroll
                    for (int iy = 0; iy < 3; ++iy) {
                        float mv = v + (float)(iy - 1);
                        if (fabsf(mv - gpy) >= C1) continue;
                        float Bx_ = fmaf(r01, mv, Ax);
                        float By_ = fmaf(r11, mv, Ay);
                        float Bz_ = fmaf(r21, mv, Az);
                        #pragma unroll
                        for (int iz = 0; iz < 3; ++iz) {
                            if (!zok[iz]) continue;
                            float moz = (float)(iz - 1);
                            float ex = fmaf(r02, moz, Bx_);
                            float ey = fmaf(r12, moz, By_);
                            float ez = fmaf(r22, moz, Bz_);
                            float wx = 1.0f - fabsf(ex);
                            float wy = 1.0f - fabsf(ey);
                            float wz = 1.0f - fabsf(ez);
                            if (wx > 0.0f && wy > 0.0f && wz > 0.0f) {
                                float wgt = wx * wy * wz;
                                float pw = spsf[(iz * 3 + iy) * 3 + ix];
                                acc = fmaf(wgt * pw, sval, acc);
                            }
                        }
                    }
                }
            }
        }
    }
    vol[idx] = acc;

    if (dslots) {  // uniform branch
        block_reduce_spread((double)acc * (double)dvec[idx], dslots);
    }
}

// r = b - Ap; p = r; rr0 += sum(r*r)
__global__ __launch_bounds__(256) void rp_init_dot_kernel(
    float* __restrict__ r, float* __restrict__ p,
    const float* __restrict__ b, const float* __restrict__ Ap,
    double* __restrict__ rr_slots)
{
    int i = blockIdx.x * 256 + threadIdx.x;
    float rv = b[i] - Ap[i];
    r[i] = rv;
    p[i] = rv;
    block_reduce_spread((double)rv * (double)rv, rr_slots);
}

// x += alpha*p; r -= alpha*Ap; rr_new += sum(r_new^2);  alpha = rr_old / pAp
__global__ __launch_bounds__(256) void update_xr_dot_kernel(
    float* __restrict__ x, float* __restrict__ r,
    const float* __restrict__ p, const float* __restrict__ Ap,
    const double* __restrict__ rr_old_slots, const double* __restrict__ pap_slots,
    double* __restrict__ rr_new_slots)
{
    float alpha = (float)(sum_slots(rr_old_slots) / sum_slots(pap_slots));
    int i = blockIdx.x * 256 + threadIdx.x;
    x[i] = fmaf(alpha, p[i], x[i]);
    float rv = fmaf(-alpha, Ap[i], r[i]);
    r[i] = rv;
    block_reduce_spread((double)rv * (double)rv, rr_new_slots);
}

// p = r + beta*p;  beta = rr_new / rr_old
__global__ __launch_bounds__(256) void update_p_kernel(
    float* __restrict__ p, const float* __restrict__ r,
    const double* __restrict__ rr_new_slots, const double* __restrict__ rr_old_slots)
{
    float beta = (float)(sum_slots(rr_new_slots) / sum_slots(rr_old_slots));
    int i = blockIdx.x * 256 + threadIdx.x;
    p[i] = fmaf(beta, p[i], r[i]);
}

__global__ __launch_bounds__(256) void relu_kernel(
    float* __restrict__ out, const float* __restrict__ x)
{
    int i = blockIdx.x * 256 + threadIdx.x;
    out[i] = fmaxf(x[i], 0.0f);
}

extern "C" void kernel_launch(void* const* d_in, const int* in_sizes, int n_in,
                              void* d_out, int out_size, void* d_ws, size_t ws_size,
                              hipStream_t stream) {
    const float* theta  = (const float*)d_in[0];  // [16,3,4]
    const float* slices = (const float*)d_in[1];  // [16,1,128,128]
    const float* volume = (const float*)d_in[2];  // [1,1,128,128,128]
    const float* psf    = (const float*)d_in[3];  // [3,3,3]
    float* out = (float*)d_out;

    char* ws = (char*)d_ws;
    float* x  = (float*)ws;
    float* r  = x  + VOX;
    float* p  = r  + VOX;
    float* Ap = p  + VOX;
    float* b  = Ap + VOX;
    float* sl = b  + VOX;
    double* sc = (double*)(sl + NPIX);
    double* rrs0 = sc;            // 64 slots * stride 32
    double* rrs1 = sc + 2048;
    double* paps = sc + 4096;
    float* cst = (float*)(sc + 6144);   // 16 * 128 floats

    const int gpix = NPIX / 256;  // 1024
    const int gvox = VOX / 256;   // 8192
    const size_t SLOTB = 2048 * sizeof(double);  // 16 KB per slot array

    prep_kernel<<<1, 512, 0, stream>>>(theta, cst);

    // x = volume (initial guess)
    hipMemcpyAsync(x, volume, VOX * sizeof(float), hipMemcpyDeviceToDevice, stream);

    // b = At(slices)
    at_gather_kernel<<<gvox, 256, 0, stream>>>(cst, slices, psf, b, nullptr, nullptr);

    // Ap = AtA(x0)
    a_kernel<<<gpix, 256, 0, stream>>>(cst, x, psf, sl);
    at_gather_kernel<<<gvox, 256, 0, stream>>>(cst, sl, psf, Ap, nullptr, nullptr);

    // r = b - Ap; p = r; rr0 = dot(r,r)
    hipMemsetAsync(rrs0, 0, SLOTB, stream);
    rp_init_dot_kernel<<<gvox, 256, 0, stream>>>(r, p, b, Ap, rrs0);

    for (int it = 0; it < 10; ++it) {
        double* rr_old = (it & 1) ? rrs1 : rrs0;
        double* rr_new = (it & 1) ? rrs0 : rrs1;

        // Ap = AtA(p), fused pAp = dot(p, Ap)
        a_kernel<<<gpix, 256, 0, stream>>>(cst, p, psf, sl);
        hipMemsetAsync(paps, 0, SLOTB, stream);
        at_gather_kernel<<<gvox, 256, 0, stream>>>(cst, sl, psf, Ap, p, paps);

        // x += alpha p; r -= alpha Ap; rr_new = dot(r,r)
        hipMemsetAsync(rr_new, 0, SLOTB, stream);
        update_xr_dot_kernel<<<gvox, 256, 0, stream>>>(x, r, p, Ap, rr_old, paps, rr_new);

        // p = r + beta p
        update_p_kernel<<<gvox, 256, 0, stream>>>(p, r, rr_new, rr_old);
    }

    // out = relu(x)
    relu_kernel<<<gvox, 256, 0, stream>>>(out, x);
}

// Round 4
// 1721.148 us; speedup vs baseline: 3.0634x; 1.2058x over previous
//
#include <hip/hip_runtime.h>
#include <math.h>

// Problem constants (match reference)
constexpr int DD = 128, HH = 128, WW = 128;
constexpr int VOX = DD * HH * WW;        // 2,097,152
constexpr int NPIX = 16 * 128 * 128;     // 262,144
constexpr int NS = 16;
constexpr float RES_RATIO = 1.5f;

// Per-slice constant block layout (floats, stride 128):
//  [0..11]  T row-major (r00 r01 r02 t0 | r10 r11 r12 t1 | r20 r21 r22 t2)
//  [12..14] tc = t + 63.5 (volume-center shift folded in)
//  [15..17] C0,C1,C2 = column L1 norms of R (exact At candidate bounds)
//  [18..20] row L1 norms of R (A pixel-cull margins)
//  [24+3k+{0,1,2}] rotated PSF offset k: R @ (ix-1, iy-1, iz-1), k=(iz*3+iy)*3+ix
constexpr int CSTR = 128;

__global__ __launch_bounds__(512) void prep_kernel(
    const float* __restrict__ theta, float* __restrict__ cst)
{
    int tid = threadIdx.x;
    int n = tid >> 5, j = tid & 31;
    if (n >= NS) return;
    const float* T = theta + n * 12;
    float* C = cst + n * CSTR;
    if (j < 12) C[j] = T[j];
    if (j == 12) {
        float r00=T[0], r01=T[1], r02=T[2],  t0=T[3];
        float r10=T[4], r11=T[5], r12=T[6],  t1=T[7];
        float r20=T[8], r21=T[9], r22=T[10], t2=T[11];
        C[12] = t0 + 63.5f; C[13] = t1 + 63.5f; C[14] = t2 + 63.5f;
        C[15] = fabsf(r00) + fabsf(r10) + fabsf(r20);  // col-x L1
        C[16] = fabsf(r01) + fabsf(r11) + fabsf(r21);  // col-y L1
        C[17] = fabsf(r02) + fabsf(r12) + fabsf(r22);  // col-z L1
        C[18] = fabsf(r00) + fabsf(r01) + fabsf(r02);  // row-x L1
        C[19] = fabsf(r10) + fabsf(r11) + fabsf(r12);  // row-y L1
        C[20] = fabsf(r20) + fabsf(r21) + fabsf(r22);  // row-z L1
    }
    if (j < 27) {
        float ox = (float)(j % 3) - 1.0f;
        float oy = (float)((j / 3) % 3) - 1.0f;
        float oz = (float)(j / 9) - 1.0f;
        C[24 + 3*j + 0] = T[0]*ox + T[1]*oy + T[2]*oz;
        C[24 + 3*j + 1] = T[4]*ox + T[5]*oy + T[6]*oz;
        C[24 + 3*j + 2] = T[8]*ox + T[9]*oy + T[10]*oz;
    }
}

// ---------------------------------------------------------------------------
// Spread-slot double reduction: 64 slots, 256B apart.
// ---------------------------------------------------------------------------
__device__ __forceinline__ void block_reduce_spread(double s, double* slots)
{
    #pragma unroll
    for (int off = 32; off > 0; off >>= 1)
        s += __shfl_down(s, off, 64);
    __shared__ double ls[4];
    if ((threadIdx.x & 63) == 0) ls[threadIdx.x >> 6] = s;
    __syncthreads();
    if (threadIdx.x == 0)
        atomicAdd(&slots[(blockIdx.x & 63) * 32], ls[0] + ls[1] + ls[2] + ls[3]);
}

__device__ __forceinline__ double sum_slots(const double* __restrict__ s)
{
    double t = 0.0;
    #pragma unroll
    for (int i = 0; i < 64; ++i) t += s[i * 32];
    return t;
}

// ---------------------------------------------------------------------------
// A: PSF-weighted trilinear gather volume -> slices (one thread per pixel)
// ---------------------------------------------------------------------------
__global__ __launch_bounds__(256) void a_kernel(
    const float* __restrict__ cst, const float* __restrict__ vol,
    const float* __restrict__ psf, float* __restrict__ out)
{
    int idx = blockIdx.x * 256 + threadIdx.x;     // exact grid: NPIX threads
    int w = idx & 127;
    int h = (idx >> 7) & 127;
    int n = idx >> 14;
    const float* C = cst + n * CSTR;
    float r00=C[0], r01=C[1];
    float r10=C[4], r11=C[5];
    float r20=C[8], r21=C[9];

    float u = (w - 63.5f) * RES_RATIO;
    float v = (h - 63.5f) * RES_RATIO;
    float px = fmaf(r00, u, fmaf(r01, v, C[12]));
    float py = fmaf(r10, u, fmaf(r11, v, C[13]));
    float pz = fmaf(r20, u, fmaf(r21, v, C[14]));

    if (px <= -1.0f - C[18] || px >= 128.0f + C[18] ||
        py <= -1.0f - C[19] || py >= 128.0f + C[19] ||
        pz <= -1.0f - C[20] || pz >= 128.0f + C[20]) {
        out[idx] = 0.0f;
        return;
    }

    float acc = 0.0f;
    for (int k = 0; k < 27; ++k) {
        float sx = px + C[24 + 3*k + 0];
        float sy = py + C[24 + 3*k + 1];
        float sz = pz + C[24 + 3*k + 2];
        if (sx <= -1.0f || sx >= 128.0f || sy <= -1.0f || sy >= 128.0f ||
            sz <= -1.0f || sz >= 128.0f) continue;
        float pw = psf[k];

        float xf = floorf(sx), yf = floorf(sy), zf = floorf(sz);
        int x0 = (int)xf, y0 = (int)yf, z0 = (int)zf;
        float fx = sx - xf, fy = sy - yf, fz = sz - zf;

        if (x0 >= 0 && x0 < 127 && y0 >= 0 && y0 < 127 && z0 >= 0 && z0 < 127) {
            const float* vp = vol + (z0 << 14) + (y0 << 7) + x0;
            float c000 = vp[0],       c001 = vp[1];
            float c010 = vp[128],     c011 = vp[129];
            float c100 = vp[16384],   c101 = vp[16385];
            float c110 = vp[16512],   c111 = vp[16513];
            float c00 = fmaf(fx, c001 - c000, c000);
            float c01 = fmaf(fx, c011 - c010, c010);
            float c10 = fmaf(fx, c101 - c100, c100);
            float c11 = fmaf(fx, c111 - c110, c110);
            float c0  = fmaf(fy, c01 - c00, c00);
            float c1  = fmaf(fy, c11 - c10, c10);
            acc = fmaf(pw, fmaf(fz, c1 - c0, c0), acc);
        } else {
            float wx0 = 1.0f - fx, wy0 = 1.0f - fy, wz0 = 1.0f - fz;
            #pragma unroll
            for (int dz = 0; dz < 2; ++dz)
            #pragma unroll
            for (int dy = 0; dy < 2; ++dy)
            #pragma unroll
            for (int dx = 0; dx < 2; ++dx) {
                int xi = x0 + dx, yi = y0 + dy, zi = z0 + dz;
                bool inb = ((unsigned)xi < 128u) & ((unsigned)yi < 128u) & ((unsigned)zi < 128u);
                if (inb) {
                    float wgt = (dx ? fx : wx0) * (dy ? fy : wy0) * (dz ? fz : wz0);
                    acc += pw * wgt * vol[(zi << 14) + (yi << 7) + xi];
                }
            }
        }
    }
    out[idx] = acc;
}

// ---------------------------------------------------------------------------
// At as a GATHER, tiled 16x16x1 per block + per-block conservative slice list.
// Block b: tile origin (tx,ty) = ((b&7)*16, ((b>>3)&7)*16), z = b>>6.
// Slice list via interval arithmetic: slice n can touch the tile only if
// |gpz(center)| < 1 + C2 + (|r02|+|r12|)*7.5.  Exact per-voxel culls follow.
// Innermost candidate body is branch-free (clamped weights).
// ---------------------------------------------------------------------------
__global__ __launch_bounds__(256) void at_gather_kernel(
    const float* __restrict__ cst, const float* __restrict__ sl,
    const float* __restrict__ psf, float* __restrict__ vol,
    const float* __restrict__ dvec, double* __restrict__ dslots)
{
    __shared__ float spsf[27];
    __shared__ unsigned smask;
    int tid = threadIdx.x;
    if (tid < 27) spsf[tid] = psf[tid];
    if (tid == 0) smask = 0u;
    __syncthreads();

    int b = blockIdx.x;
    int tx = (b & 7) << 4, ty = ((b >> 3) & 7) << 4, z = b >> 6;
    int x = tx + (tid & 15), y = ty + (tid >> 4);

    float qx = (float)x, qy = (float)y, qz = (float)z;

    if (tid < NS) {
        const float* C = cst + tid * CSTR;
        float gx = (float)tx + 7.5f - C[12];
        float gy = (float)ty + 7.5f - C[13];
        float gz = qz - C[14];
        float gpz = C[2]*gx + C[6]*gy + C[10]*gz;
        float margin = (fabsf(C[2]) + fabsf(C[6])) * 7.5f;
        if (fabsf(gpz) < 1.0f + C[17] + margin)
            atomicOr(&smask, 1u << tid);
    }
    __syncthreads();
    unsigned mask = smask;

    float acc = 0.0f;
    while (mask) {
        int n = __ffs(mask) - 1;
        mask &= mask - 1;
        const float* C = cst + n * CSTR;
        float r00=C[0], r01=C[1], r02=C[2];
        float r10=C[4], r11=C[5], r12=C[6];
        float r20=C[8], r21=C[9], r22=C[10];
        float gx = qx - C[12], gy = qy - C[13], gz = qz - C[14];
        float C0 = C[15], C1 = C[16], C2 = C[17];

        float gpz = r02*gx + r12*gy + r22*gz;
        if (fabsf(gpz) >= 1.0f + C2) continue;
        float gpx = r00*gx + r10*gy + r20*gz;
        if (fabsf(gpx) >= 96.25f + C0) continue;
        float gpy = r01*gx + r11*gy + r21*gz;
        if (fabsf(gpy) >= 96.25f + C1) continue;

        const float inv15 = 1.0f / 1.5f;
        float Bxb = 1.0f + C0, Byb = 1.0f + C1;
        int wlo = (int)ceilf (63.5f + (gpx - Bxb) * inv15);
        int whi = (int)floorf(63.5f + (gpx + Bxb) * inv15);
        wlo = max(wlo, 0); whi = min(whi, 127);
        int hlo = (int)ceilf (63.5f + (gpy - Byb) * inv15);
        int hhi = (int)floorf(63.5f + (gpy + Byb) * inv15);
        hlo = max(hlo, 0); hhi = min(hhi, 127);

        bool zok[3];
        #pragma unroll
        for (int iz = 0; iz < 3; ++iz)
            zok[iz] = fabsf((float)(iz - 1) - gpz) < C2;

        const float* slice_n = sl + (n << 14);

        for (int w = wlo; w <= whi; ++w) {
            float u = (w - 63.5f) * RES_RATIO;
            #pragma unroll
            for (int ix = 0; ix < 3; ++ix) {
                float mu = u + (float)(ix - 1);
                if (fabsf(mu - gpx) >= C0) continue;
                float Ax = fmaf(r00, mu, -gx);
                float Ay = fmaf(r10, mu, -gy);
                float Az = fmaf(r20, mu, -gz);
                for (int h = hlo; h <= hhi; ++h) {
                    float v = (h - 63.5f) * RES_RATIO;
                    float sval = slice_n[(h << 7) + w];
                    #pragma unroll
                    for (int iy = 0; iy < 3; ++iy) {
                        float mv = v + (float)(iy - 1);
                        if (fabsf(mv - gpy) >= C1) continue;
                        float Bx_ = fmaf(r01, mv, Ax);
                        float By_ = fmaf(r11, mv, Ay);
                        float Bz_ = fmaf(r21, mv, Az);
                        #pragma unroll
                        for (int iz = 0; iz < 3; ++iz) {
                            if (!zok[iz]) continue;
                            float moz = (float)(iz - 1);
                            // branch-free clamped trilinear weight
                            float wx = fmaxf(1.0f - fabsf(fmaf(r02, moz, Bx_)), 0.0f);
                            float wy = fmaxf(1.0f - fabsf(fmaf(r12, moz, By_)), 0.0f);
                            float wz = fmaxf(1.0f - fabsf(fmaf(r22, moz, Bz_)), 0.0f);
                            float wgt = wx * wy * wz;
                            acc = fmaf(wgt * spsf[(iz * 3 + iy) * 3 + ix], sval, acc);
                        }
                    }
                }
            }
        }
    }

    int idx = (z << 14) + (y << 7) + x;
    vol[idx] = acc;

    if (dslots) {  // uniform branch
        block_reduce_spread((double)acc * (double)dvec[idx], dslots);
    }
}

// r = b - Ap; p = r; rr0 += sum(r*r)
__global__ __launch_bounds__(256) void rp_init_dot_kernel(
    float* __restrict__ r, float* __restrict__ p,
    const float* __restrict__ b, const float* __restrict__ Ap,
    double* __restrict__ rr_slots)
{
    int i = blockIdx.x * 256 + threadIdx.x;
    float rv = b[i] - Ap[i];
    r[i] = rv;
    p[i] = rv;
    block_reduce_spread((double)rv * (double)rv, rr_slots);
}

// x += alpha*p; r -= alpha*Ap; rr_new += sum(r_new^2);  alpha = rr_old / pAp
__global__ __launch_bounds__(256) void update_xr_dot_kernel(
    float* __restrict__ x, float* __restrict__ r,
    const float* __restrict__ p, const float* __restrict__ Ap,
    const double* __restrict__ rr_old_slots, const double* __restrict__ pap_slots,
    double* __restrict__ rr_new_slots)
{
    float alpha = (float)(sum_slots(rr_old_slots) / sum_slots(pap_slots));
    int i = blockIdx.x * 256 + threadIdx.x;
    x[i] = fmaf(alpha, p[i], x[i]);
    float rv = fmaf(-alpha, Ap[i], r[i]);
    r[i] = rv;
    block_reduce_spread((double)rv * (double)rv, rr_new_slots);
}

// p = r + beta*p;  beta = rr_new / rr_old
__global__ __launch_bounds__(256) void update_p_kernel(
    float* __restrict__ p, const float* __restrict__ r,
    const double* __restrict__ rr_new_slots, const double* __restrict__ rr_old_slots)
{
    float beta = (float)(sum_slots(rr_new_slots) / sum_slots(rr_old_slots));
    int i = blockIdx.x * 256 + threadIdx.x;
    p[i] = fmaf(beta, p[i], r[i]);
}

__global__ __launch_bounds__(256) void relu_kernel(
    float* __restrict__ out, const float* __restrict__ x)
{
    int i = blockIdx.x * 256 + threadIdx.x;
    out[i] = fmaxf(x[i], 0.0f);
}

extern "C" void kernel_launch(void* const* d_in, const int* in_sizes, int n_in,
                              void* d_out, int out_size, void* d_ws, size_t ws_size,
                              hipStream_t stream) {
    const float* theta  = (const float*)d_in[0];  // [16,3,4]
    const float* slices = (const float*)d_in[1];  // [16,1,128,128]
    const float* volume = (const float*)d_in[2];  // [1,1,128,128,128]
    const float* psf    = (const float*)d_in[3];  // [3,3,3]
    float* out = (float*)d_out;

    char* ws = (char*)d_ws;
    float* x  = (float*)ws;
    float* r  = x  + VOX;
    float* p  = r  + VOX;
    float* Ap = p  + VOX;
    float* b  = Ap + VOX;
    float* sl = b  + VOX;
    double* sc = (double*)(sl + NPIX);
    double* rrs0 = sc;            // 64 slots * stride 32
    double* rrs1 = sc + 2048;
    double* paps = sc + 4096;
    float* cst = (float*)(sc + 6144);   // 16 * 128 floats

    const int gpix = NPIX / 256;  // 1024
    const int gvox = VOX / 256;   // 8192
    const size_t SLOTB = 2048 * sizeof(double);

    prep_kernel<<<1, 512, 0, stream>>>(theta, cst);

    // x = volume (initial guess)
    hipMemcpyAsync(x, volume, VOX * sizeof(float), hipMemcpyDeviceToDevice, stream);

    // b = At(slices)
    at_gather_kernel<<<gvox, 256, 0, stream>>>(cst, slices, psf, b, nullptr, nullptr);

    // Ap = AtA(x0)
    a_kernel<<<gpix, 256, 0, stream>>>(cst, x, psf, sl);
    at_gather_kernel<<<gvox, 256, 0, stream>>>(cst, sl, psf, Ap, nullptr, nullptr);

    // r = b - Ap; p = r; rr0 = dot(r,r)
    hipMemsetAsync(rrs0, 0, SLOTB, stream);
    rp_init_dot_kernel<<<gvox, 256, 0, stream>>>(r, p, b, Ap, rrs0);

    for (int it = 0; it < 10; ++it) {
        double* rr_old = (it & 1) ? rrs1 : rrs0;
        double* rr_new = (it & 1) ? rrs0 : rrs1;

        // Ap = AtA(p), fused pAp = dot(p, Ap)
        a_kernel<<<gpix, 256, 0, stream>>>(cst, p, psf, sl);
        hipMemsetAsync(paps, 0, SLOTB, stream);
        at_gather_kernel<<<gvox, 256, 0, stream>>>(cst, sl, psf, Ap, p, paps);

        // x += alpha p; r -= alpha Ap; rr_new = dot(r,r)
        hipMemsetAsync(rr_new, 0, SLOTB, stream);
        update_xr_dot_kernel<<<gvox, 256, 0, stream>>>(x, r, p, Ap, rr_old, paps, rr_new);

        // p = r + beta p
        update_p_kernel<<<gvox, 256, 0, stream>>>(p, r, rr_new, rr_old);
    }

    // out = relu(x)
    relu_kernel<<<gvox, 256, 0, stream>>>(out, x);
}